// Round 3
// baseline (450.346 us; speedup 1.0000x reference)
//
#include <hip/hip_runtime.h>
#include <hip/hip_bf16.h>
#include <stdint.h>

// Problem constants
#define INPUT_SIZE   736
#define PLANE_ELEMS  (736*736)        // 541696
#define N_RINGS      368
#define PATCH_LEN    768
#define EMBED        768
#define BATCH        32
#define KDIM         768              // 3*16*16
#define M_TOTAL      (BATCH*23*48)    // 35328 = 138*256
#define P_PER_BATCH  1104             // 23*48
#define OUT_BATCH_STRIDE 847872       // 768*1104
#define GATHER_T     (N_RINGS*PATCH_LEN)   // 282624 table entries

typedef __bf16 bf16x8 __attribute__((ext_vector_type(8)));
typedef float  floatx4 __attribute__((ext_vector_type(4)));

static __device__ __forceinline__ unsigned short bf16bits(float f) {
    __hip_bfloat16 h = __float2bfloat16(f);
    return *reinterpret_cast<unsigned short*>(&h);
}

#define GLDS(gptr, lptr) __builtin_amdgcn_global_load_lds( \
    (const __attribute__((address_space(1))) void*)(const void*)(gptr), \
    (__attribute__((address_space(3))) void*)(void*)(lptr), 16, 0, 0)
#define FENCE() asm volatile("" ::: "memory")
#define BAR()   do { FENCE(); __builtin_amdgcn_s_barrier(); FENCE(); } while (0)

// ---------------------------------------------------------------------------
// Kernel 1: cast conv_w (fp32, [E=768][K=768] flat) -> bf16 Wb
// ---------------------------------------------------------------------------
__global__ void wcast_kernel(const float* __restrict__ wsrc,
                             __hip_bfloat16* __restrict__ Wb) {
    int i = blockIdx.x * 256 + threadIdx.x;   // grid covers 589824 exactly
    Wb[i] = __float2bfloat16(wsrc[i]);
}

// ---------------------------------------------------------------------------
// Kernel 1b: pack (idx0, idx1, w) -> 8B record {i0, (w16<<16)|(i1-i0)}
// ---------------------------------------------------------------------------
__global__ void pack_kernel(const int*   __restrict__ idx0,
                            const int*   __restrict__ idx1,
                            const float* __restrict__ w,
                            int2* __restrict__ P) {
    int t = blockIdx.x * 256 + threadIdx.x;   // grid 1104*256 = 282624 exact
    int i0 = idx0[t];
    int d  = idx1[t] - i0;
    unsigned w16 = (unsigned)(w[t] * 65536.0f);
    if (w16 > 65535u) w16 = 65535u;
    P[t] = make_int2(i0, (int)((w16 << 16) | ((unsigned)d & 0xFFFFu)));
}

// ---------------------------------------------------------------------------
// Kernel 2: gather + lerp -> A[m][k] bf16  (UNCHANGED from R5 for attribution)
//   Evidence through R5: time == ~1.5 cy per scattered lane-load (212K/CU)
//   regardless of instruction mix (R4) and footprint compactness (R5).
// ---------------------------------------------------------------------------
__global__ void gather_kernel(const float* __restrict__ x,
                              const int2*  __restrict__ P,
                              __hip_bfloat16* __restrict__ A) {
    int b    = blockIdx.x;          // ((n*3+c)*23 + band)*2 + half
    int half = b & 1;
    int bb   = b >> 1;
    int band = bb % 23;
    int nc   = bb / 23;             // n*3+c
    int c    = nc % 3;
    int n    = nc / 3;
    const float* plane = x + (size_t)nc * PLANE_ELEMS;

    int wv   = threadIdx.x >> 6;    // wave 0..3
    int lane = threadIdx.x & 63;
    int rr   = lane >> 2;           // ring within band, 0..15 (radial-major)
    int ps   = lane & 3;            // angle-pair slot, 0..3
    int aw   = wv >> 1;
    int hb   = wv & 1;
    int r    = band * 16 + rr;

    int tbase = r * PATCH_LEN + half * 384 + aw * 16 + hb * 8 + ps * 2;
    int k     = c * 256 + rr * 16 + hb * 8 + ps * 2;
    size_t mbase = (size_t)(n * P_PER_BATCH + band * 48 + half * 24 + aw);
    __hip_bfloat16* aptr = A + mbase * KDIM + k;

    #pragma unroll 4
    for (int it = 0; it < 12; it++) {
        int4 q = *reinterpret_cast<const int4*>(&P[tbase + it * 32]);
        int   i0a = q.x;
        int   i1a = i0a + (int)(short)((unsigned)q.y & 0xFFFFu);
        float wa  = (float)((unsigned)q.y >> 16) * (1.0f / 65536.0f);
        float va  = plane[i0a] * (1.0f - wa) + plane[i1a] * wa;
        int   i0b = q.z;
        int   i1b = i0b + (int)(short)((unsigned)q.w & 0xFFFFu);
        float wb  = (float)((unsigned)q.w >> 16) * (1.0f / 65536.0f);
        float vb  = plane[i0b] * (1.0f - wb) + plane[i1b] * wb;
        *reinterpret_cast<ushort2*>(aptr + (size_t)(it * 2) * KDIM) =
            make_ushort2(bf16bits(va), bf16bits(vb));
    }
}

// ---------------------------------------------------------------------------
// Kernel 3: GEMM  C[m][e] = sum_k A[m][k]*Wb[e][k] + bias[e]
//   R6 rewrite: deep-pipelined 256x128 tile, BK=64, 8 waves (4M x 2N),
//   per-wave 64x64 = acc[4][4] of 16x16x32 MFMA.
//   - A: 3 LDS slots (32KB each) staged 2 K-tiles ahead (~8 phases of cover
//     > 900cy HBM latency).  B: 2 slots (16KB), 1 K-tile ahead (L2-hot:
//     only 6 distinct B panels; Wb = 1.2MB).  LDS total 128KB (m201-proven).
//   - Counted s_waitcnt vmcnt(4) ONCE per K-tile (the 4 newest = A(kt+2)
//     loads stay in flight across the barrier) -- never drains to 0 (T4).
//   - XOR swizzle (T2): ds_read of a column-slice at 128B row stride is a
//     16-way bank conflict; fix slot' = slot ^ (row&7).  global_load_lds
//     writes LINEAR dest; the SOURCE column is inverse-swizzled (rule #21:
//     both-sides-or-neither, same involution).
//   - setprio(1) around each 16-MFMA cluster (T5); sched_barrier(0) after
//     each pre-MFMA barrier (rule #18).
// ---------------------------------------------------------------------------
__global__ __launch_bounds__(512) void gemm_kernel(
        const __hip_bfloat16* __restrict__ Ap,  // [35328][768]
        const __hip_bfloat16* __restrict__ Wb,  // [768][768] (E,K) = B^T
        const float* __restrict__ cb,           // [768]
        float* __restrict__ out)                // [32][768][1104]
{
    __shared__ __hip_bfloat16 As[3 * 256 * 64];   // 96 KiB, 3 K-tile slots
    __shared__ __hip_bfloat16 Bs[2 * 128 * 64];   // 32 KiB, 2 K-tile slots

    const int tid  = threadIdx.x;
    const int lane = tid & 63;
    const int wv   = tid >> 6;     // 0..7
    const int wm   = wv >> 1;      // wave row 0..3  (64 m-rows each)
    const int wn   = wv & 1;       // wave col 0..1  (64 e-cols each)
    const int quad = lane >> 4;
    const int l16  = lane & 15;

    const int bn = blockIdx.x;     // 0..5   (embed tiles of 128)
    const int bm = blockIdx.y;     // 0..137 (m tiles of 256)

    floatx4 acc[4][4];
    #pragma unroll
    for (int i = 0; i < 4; i++)
        #pragma unroll
        for (int j = 0; j < 4; j++)
            acc[i][j] = (floatx4){0.f, 0.f, 0.f, 0.f};

    // ---- staging address precompute (linear LDS dest, inverse-swz source)
    // A: 4 loads/thread/K-tile, u = l*512+tid -> LDS row u>>3, slot8 u&7
    const __hip_bfloat16* aG[4]; __hip_bfloat16* aL[4];
    #pragma unroll
    for (int l = 0; l < 4; l++) {
        int u   = l * 512 + tid;
        int row = u >> 3;
        int col = ((u & 7) ^ (row & 7)) * 8;      // inverse-swizzled source
        aG[l] = Ap + (size_t)(bm * 256 + row) * KDIM + col;
        aL[l] = As + u * 8;                        // + slot*16384 at stage
    }
    // B: 2 loads/thread/K-tile
    const __hip_bfloat16* bG[2]; __hip_bfloat16* bL[2];
    #pragma unroll
    for (int l = 0; l < 2; l++) {
        int u   = l * 512 + tid;
        int row = u >> 3;
        int col = ((u & 7) ^ (row & 7)) * 8;
        bG[l] = Wb + (size_t)(bn * 128 + row) * KDIM + col;
        bL[l] = Bs + u * 8;                        // + slot*8192 at stage
    }

    // ---- prologue: A(0) slot0, B(0) slot0, A(1) slot1; wait A0,B0; keep A1
    #pragma unroll
    for (int l = 0; l < 4; l++) GLDS(aG[l], aL[l]);
    #pragma unroll
    for (int l = 0; l < 2; l++) GLDS(bG[l], bL[l]);
    #pragma unroll
    for (int l = 0; l < 4; l++) GLDS(aG[l] + 64, aL[l] + 16384);
    asm volatile("s_waitcnt vmcnt(4)" ::: "memory");
    BAR();

    bf16x8 afr[2][2], bfr[4][2];

    for (int kt = 0; kt < 12; kt++) {
        const int sA  = kt % 3;
        const int sB  = kt & 1;
        const int sA2 = (kt + 2) % 3;        // A prefetch slot
        const int sB1 = (kt + 1) & 1;        // B prefetch slot
        const __hip_bfloat16* asl = As + sA * 16384;
        const __hip_bfloat16* bsl = Bs + sB * 8192;

        // ================= phase A: C rows mi 0..1 =================
        #pragma unroll
        for (int mi = 0; mi < 2; mi++) {
            int r = wm * 64 + mi * 16 + l16;
            #pragma unroll
            for (int kk = 0; kk < 2; kk++) {
                int sl = (kk * 4 + quad) ^ (r & 7);
                afr[mi][kk] = *(const bf16x8*)(asl + r * 64 + sl * 8);
            }
        }
        #pragma unroll
        for (int ni = 0; ni < 4; ni++) {
            int r = wn * 64 + ni * 16 + l16;
            #pragma unroll
            for (int kk = 0; kk < 2; kk++) {
                int sl = (kk * 4 + quad) ^ (r & 7);
                bfr[ni][kk] = *(const bf16x8*)(bsl + r * 64 + sl * 8);
            }
        }
        // stage: B(kt+1) both loads, A(kt+2) load 0
        GLDS(bG[0] + (kt + 1) * 64, bL[0] + sB1 * 8192);
        GLDS(bG[1] + (kt + 1) * 64, bL[1] + sB1 * 8192);
        GLDS(aG[0] + (kt + 2) * 64, aL[0] + sA2 * 16384);
        BAR();
        __builtin_amdgcn_sched_barrier(0);
        __builtin_amdgcn_s_setprio(1);
        #pragma unroll
        for (int ni = 0; ni < 4; ni++)
            #pragma unroll
            for (int kk = 0; kk < 2; kk++) {
                acc[0][ni] = __builtin_amdgcn_mfma_f32_16x16x32_bf16(
                                 afr[0][kk], bfr[ni][kk], acc[0][ni], 0, 0, 0);
                acc[1][ni] = __builtin_amdgcn_mfma_f32_16x16x32_bf16(
                                 afr[1][kk], bfr[ni][kk], acc[1][ni], 0, 0, 0);
            }
        __builtin_amdgcn_s_setprio(0);
        BAR();

        // ================= phase B: C rows mi 2..3 =================
        #pragma unroll
        for (int mi = 0; mi < 2; mi++) {
            int r = wm * 64 + (mi + 2) * 16 + l16;
            #pragma unroll
            for (int kk = 0; kk < 2; kk++) {
                int sl = (kk * 4 + quad) ^ (r & 7);
                afr[mi][kk] = *(const bf16x8*)(asl + r * 64 + sl * 8);
            }
        }
        // stage: A(kt+2) loads 1..3
        GLDS(aG[1] + (kt + 2) * 64, aL[1] + sA2 * 16384);
        GLDS(aG[2] + (kt + 2) * 64, aL[2] + sA2 * 16384);
        GLDS(aG[3] + (kt + 2) * 64, aL[3] + sA2 * 16384);
        BAR();
        __builtin_amdgcn_sched_barrier(0);
        __builtin_amdgcn_s_setprio(1);
        #pragma unroll
        for (int ni = 0; ni < 4; ni++)
            #pragma unroll
            for (int kk = 0; kk < 2; kk++) {
                acc[2][ni] = __builtin_amdgcn_mfma_f32_16x16x32_bf16(
                                 afr[0][kk], bfr[ni][kk], acc[2][ni], 0, 0, 0);
                acc[3][ni] = __builtin_amdgcn_mfma_f32_16x16x32_bf16(
                                 afr[1][kk], bfr[ni][kk], acc[3][ni], 0, 0, 0);
            }
        __builtin_amdgcn_s_setprio(0);
        // counted wait: gate A(kt+1)+B(kt+1); leave A(kt+2)'s 4 loads in flight
        asm volatile("s_waitcnt vmcnt(4)" ::: "memory");
        BAR();
    }

    // ---------------- epilogue: direct float4 stores ----------------------
    const int m0 = bm * 256 + wm * 64;
    const int e0 = bn * 128 + wn * 64;
    #pragma unroll
    for (int ni = 0; ni < 4; ni++) {
        int eg = e0 + ni * 16 + l16;
        float bias = cb[eg];
        #pragma unroll
        for (int mi = 0; mi < 4; mi++) {
            int mg = m0 + mi * 16 + quad * 4;
            int nb = mg / P_PER_BATCH;          // magic-mul
            int p  = mg - nb * P_PER_BATCH;
            floatx4 v = acc[mi][ni];
            v[0] += bias; v[1] += bias; v[2] += bias; v[3] += bias;
            *(floatx4*)(out + (size_t)nb * OUT_BATCH_STRIDE
                            + (size_t)eg * P_PER_BATCH + p) = v;
        }
    }
}

// ---------------------------------------------------------------------------
extern "C" void kernel_launch(void* const* d_in, const int* in_sizes, int n_in,
                              void* d_out, int out_size, void* d_ws, size_t ws_size,
                              hipStream_t stream) {
    const float* x      = (const float*)d_in[0];   // (32,3,736,736)
    const float* conv_w = (const float*)d_in[1];   // (768,3,16,16) = (768,768)
    const float* conv_b = (const float*)d_in[2];   // (768,)
    const int*   idx0   = (const int*)  d_in[3];   // (368*768,)
    const int*   idx1   = (const int*)  d_in[4];
    const float* w      = (const float*)d_in[5];
    float* out = (float*)d_out;

    __hip_bfloat16* A  = (__hip_bfloat16*)d_ws;                 // 54.3 MB
    __hip_bfloat16* Wb = A + (size_t)M_TOTAL * KDIM;            // +1.2 MB
    int2*           P  = (int2*)(Wb + (size_t)EMBED * KDIM);    // +2.3 MB

    // 1) weight cast: 589824 elements
    wcast_kernel<<<dim3(EMBED * KDIM / 256), dim3(256), 0, stream>>>(conv_w, Wb);

    // 1b) pack gather tables: 282624 entries
    pack_kernel<<<dim3(GATHER_T / 256), dim3(256), 0, stream>>>(idx0, idx1, w, P);

    // 2) gather+lerp -> A : one block per (n, c, band, half)
    gather_kernel<<<dim3(BATCH * 3 * (N_RINGS / 16) * 2), dim3(256), 0, stream>>>(
        x, P, A);

    // 3) GEMM + bias -> out : 256x128 tiles, 512 threads
    gemm_kernel<<<dim3(EMBED / 128, M_TOTAL / 256), dim3(512), 0, stream>>>(
        A, Wb, conv_b, out);
}